// Round 1
// baseline (5281.905 us; speedup 1.0000x reference)
//
#include <hip/hip_runtime.h>
#include <hip/hip_bf16.h>

#define LSEQ 2048
#define NB 32

// ---------- dtype helpers ----------
__device__ __forceinline__ float ldf(const float* p){ return *p; }
__device__ __forceinline__ float ldf(const __hip_bfloat16* p){ return __bfloat162float(*p); }

__device__ __forceinline__ unsigned short f2b(float f){
  __hip_bfloat16 h = __float2bfloat16(f);
  return *reinterpret_cast<unsigned short*>(&h);
}
__device__ __forceinline__ float b2f_bits(unsigned short u){
  unsigned int x = ((unsigned int)u) << 16; return __uint_as_float(x);
}
__device__ __forceinline__ void st4(float* p, float a, float b, float c, float d){
  *(float4*)p = make_float4(a,b,c,d);
}
__device__ __forceinline__ void st4(__hip_bfloat16* p, float a, float b, float c, float d){
  ushort4 u = make_ushort4(f2b(a), f2b(b), f2b(c), f2b(d));
  *(ushort4*)p = u;
}
__device__ __forceinline__ void ld4(const float* p, float&a,float&b,float&c,float&d){
  float4 v = *(const float4*)p; a=v.x;b=v.y;c=v.z;d=v.w;
}
__device__ __forceinline__ void ld4(const __hip_bfloat16* p, float&a,float&b,float&c,float&d){
  ushort4 v = *(const ushort4*)p;
  a=b2f_bits(v.x); b=b2f_bits(v.y); c=b2f_bits(v.z); d=b2f_bits(v.w);
}

__device__ __forceinline__ float wave_min(float v){
  #pragma unroll
  for (int off = 32; off; off >>= 1) v = fminf(v, __shfl_xor(v, off, 64));
  return v;
}

// ---------- row preprocessing: stats + find_peaks + normalize ----------
__global__ __launch_bounds__(256)
void row_prep(const float* __restrict__ x, float* __restrict__ h0)
{
  const int b = blockIdx.x, tid = threadIdx.x;
  const int lane = tid & 63, wid = tid >> 6;
  __shared__ float xs[LSEQ];
  __shared__ unsigned char cand[LSEQ], kA[LSEQ], kB[LSEQ], peaks[LSEQ];
  __shared__ int s_list[256];
  __shared__ int s_changed, s_cnt;
  __shared__ float s_redA[4], s_redB[4];
  __shared__ float s_mx, s_mean, s_std;

  const float* xr = x + (size_t)b * LSEQ;
  for (int i = tid; i < LSEQ/4; i += 256) ((float4*)xs)[i] = ((const float4*)xr)[i];
  __syncthreads();

  // max + sum
  float vmax = -__builtin_inff(), vsum = 0.f;
  for (int i = tid; i < LSEQ; i += 256) { float v = xs[i]; vmax = fmaxf(vmax, v); vsum += v; }
  #pragma unroll
  for (int off = 32; off; off >>= 1){
    vmax = fmaxf(vmax, __shfl_xor(vmax, off, 64));
    vsum += __shfl_xor(vsum, off, 64);
  }
  if (lane == 0){ s_redA[wid] = vmax; s_redB[wid] = vsum; }
  __syncthreads();
  if (tid == 0){
    s_mx   = fmaxf(fmaxf(s_redA[0], s_redA[1]), fmaxf(s_redA[2], s_redA[3]));
    s_mean = (s_redB[0]+s_redB[1]+s_redB[2]+s_redB[3]) * (1.f/(float)LSEQ);
  }
  __syncthreads();
  const float m = s_mean, mx = s_mx;

  // sum of squared deviations (two-pass, matches jnp.std ddof=1)
  float vss = 0.f;
  for (int i = tid; i < LSEQ; i += 256){ float d = xs[i]-m; vss += d*d; }
  #pragma unroll
  for (int off = 32; off; off >>= 1) vss += __shfl_xor(vss, off, 64);
  if (lane == 0) s_redA[wid] = vss;
  __syncthreads();
  if (tid == 0) s_std = sqrtf((s_redA[0]+s_redA[1]+s_redA[2]+s_redA[3]) / (float)(LSEQ-1));
  __syncthreads();
  const float sd = s_std;

  // candidates: strict interior local max, height filter
  const float hthr = 0.1f * mx;
  for (int i = tid; i < LSEQ; i += 256) {
    unsigned char c = 0;
    if (i >= 1 && i <= LSEQ-2) {
      float v = xs[i];
      c = (v > xs[i-1]) && (v > xs[i+1]) && (v >= hthr);
    }
    cand[i] = c; kA[i] = c; peaks[i] = 0;
  }
  if (tid == 0) s_changed = 0;
  __syncthreads();

  // Jacobi fixpoint of the greedy distance filter (DIST=10)
  unsigned char* cur = kA; unsigned char* nxt = kB;
  for (int it = 0; it < LSEQ; ++it) {
    int ch = 0;
    for (int i = tid; i < LSEQ; i += 256) {
      unsigned char nk = cand[i];
      if (nk) {
        float xi = xs[i];
        int j0 = (i-9 < 0) ? 0 : i-9;
        int j1 = (i+9 > LSEQ-1) ? LSEQ-1 : i+9;
        for (int j = j0; j <= j1; ++j) {
          if (j == i) continue;
          if (cur[j] && (xs[j] > xi || (xs[j] == xi && j < i))) { nk = 0; break; }
        }
      }
      nxt[i] = nk;
      ch |= (nk != cur[i]);
    }
    if (ch) s_changed = 1;
    __syncthreads();
    int chg = s_changed;
    __syncthreads();
    if (tid == 0) s_changed = 0;
    unsigned char* t_ = cur; cur = nxt; nxt = t_;
    __syncthreads();
    if (!chg) break;
  }

  // compact surviving candidates
  if (tid == 0) s_cnt = 0;
  __syncthreads();
  for (int i = tid; i < LSEQ; i += 256)
    if (cur[i]) { int s = atomicAdd(&s_cnt, 1); if (s < 256) s_list[s] = i; }
  __syncthreads();
  int M = s_cnt; if (M > 256) M = 256;
  const float pthr = 0.05f * mx;

  // prominence per candidate: wave-cooperative nearest-greater scans
  for (int c = wid; c < M; c += 4) {
    int p = s_list[c]; float xp = xs[p];
    float lmin = xp;
    for (int s = 0;; ++s) {
      int idx = p - 64*(s+1) + lane;
      bool valid = idx >= 0;
      float v = valid ? xs[idx] : 0.f;
      unsigned long long mk = __ballot(valid && (v > xp));
      if (mk) {
        int hb = 63 - __builtin_clzll(mk);
        float v2 = (lane > hb) ? v : __builtin_inff();
        lmin = fminf(lmin, wave_min(v2));
        break;
      }
      float v2 = valid ? v : __builtin_inff();
      lmin = fminf(lmin, wave_min(v2));
      if (p - 64*(s+1) <= 0) break;
    }
    float rmin = xp;
    for (int s = 0;; ++s) {
      int idx = p + 1 + 64*s + lane;
      bool valid = idx < LSEQ;
      float v = valid ? xs[idx] : 0.f;
      unsigned long long mk = __ballot(valid && (v > xp));
      if (mk) {
        int lb_ = __builtin_ctzll(mk);
        float v2 = (lane < lb_) ? v : __builtin_inff();
        rmin = fminf(rmin, wave_min(v2));
        break;
      }
      float v2 = valid ? v : __builtin_inff();
      rmin = fminf(rmin, wave_min(v2));
      if (p + 64 + 64*s >= LSEQ-1) break;
    }
    if (lane == 0 && (xp - fmaxf(lmin, rmin)) >= pthr) peaks[p] = 1;
  }
  __syncthreads();

  const float inv = 1.f / (sd + 1e-5f);
  for (int i = tid; i < LSEQ; i += 256) {
    float w_ = 1.f + 0.1f * (float)peaks[i];
    h0[(size_t)b*LSEQ + i] = (w_ * (xs[i] - m)) * inv;
  }
}

// ---------- conv1d + bias, folded-BN+relu on input, stats accumulation ----------
template<int CIN, int COUT, int K, int CC, bool BN_IN, typename Tin, typename Tout>
__global__ __launch_bounds__(256)
void conv_bn(const Tin* __restrict__ in, const float* __restrict__ w,
             const float* __restrict__ cb, const float* __restrict__ scale,
             const float* __restrict__ shift, Tout* __restrict__ out,
             float* __restrict__ S1, float* __restrict__ S2)
{
  constexpr int LT = 64, CT = 64, BT = 4, PAD = K/2, XW = LT + K - 1;
  static_assert(CIN % CC == 0, "CC");
  static_assert(K % 5 == 0, "K");
  __shared__ float Xs[CC][BT][XW];
  __shared__ float Ws[CC][K][CT];

  const int tid = threadIdx.x;
  const int lt = tid & 15, cg = tid >> 4;
  const int l0 = blockIdx.x * LT;
  const int co0 = blockIdx.y * CT;
  const int b0 = blockIdx.z * BT;

  float acc[BT][4][4];
  #pragma unroll
  for (int bb=0; bb<BT; ++bb)
    #pragma unroll
    for (int u=0; u<4; ++u)
      #pragma unroll
      for (int v=0; v<4; ++v) acc[bb][u][v] = 0.f;

  for (int ci0 = 0; ci0 < CIN; ci0 += CC) {
    // stage input tile (with folded BN+relu of previous layer)
    for (int idx = tid; idx < CC*BT*XW; idx += 256) {
      int ci = idx / (BT*XW); int r = idx - ci*(BT*XW);
      int bb = r / XW; int pos = r - bb*XW;
      int gl = l0 + pos - PAD;
      float v = 0.f;
      if (gl >= 0 && gl < LSEQ) {
        v = ldf(in + ((size_t)(b0+bb)*CIN + (ci0+ci))*LSEQ + gl);
        if (BN_IN) v = fmaxf(fmaf(v, scale[ci0+ci], shift[ci0+ci]), 0.f);
      }
      Xs[ci][bb][pos] = v;
    }
    // stage weights [ci][t][co]
    for (int idx = tid; idx < CC*K*CT; idx += 256) {
      int ci = idx / (K*CT); int r = idx - ci*(K*CT);
      int t = r / CT; int co = r - t*CT;
      Ws[ci][t][co] = w[((size_t)(co0+co)*CIN + (ci0+ci))*K + t];
    }
    __syncthreads();

    #pragma unroll 1
    for (int ci = 0; ci < CC; ++ci) {
      #pragma unroll 1
      for (int t = 0; t < K; t += 5) {
        float4 wv[5];
        #pragma unroll
        for (int tp = 0; tp < 5; ++tp) wv[tp] = *(const float4*)&Ws[ci][t+tp][cg*4];
        #pragma unroll
        for (int bb = 0; bb < BT; ++bb) {
          float xv[8];
          #pragma unroll
          for (int q = 0; q < 8; ++q) xv[q] = Xs[ci][bb][lt*4 + t + q];
          #pragma unroll
          for (int tp = 0; tp < 5; ++tp) {
            #pragma unroll
            for (int v = 0; v < 4; ++v) {
              float xx = xv[tp+v];
              acc[bb][0][v] = fmaf(wv[tp].x, xx, acc[bb][0][v]);
              acc[bb][1][v] = fmaf(wv[tp].y, xx, acc[bb][1][v]);
              acc[bb][2][v] = fmaf(wv[tp].z, xx, acc[bb][2][v]);
              acc[bb][3][v] = fmaf(wv[tp].w, xx, acc[bb][3][v]);
            }
          }
        }
      }
    }
    __syncthreads();
  }

  // epilogue: bias, store, per-channel stats
  float bias[4];
  #pragma unroll
  for (int u=0; u<4; ++u) bias[u] = cb[co0 + cg*4 + u];
  float p1[4] = {0,0,0,0}, p2[4] = {0,0,0,0};
  #pragma unroll
  for (int bb=0; bb<BT; ++bb) {
    #pragma unroll
    for (int u=0; u<4; ++u) {
      float y0 = acc[bb][u][0] + bias[u];
      float y1 = acc[bb][u][1] + bias[u];
      float y2 = acc[bb][u][2] + bias[u];
      float y3 = acc[bb][u][3] + bias[u];
      p1[u] += y0+y1+y2+y3;
      p2[u] += y0*y0 + y1*y1 + y2*y2 + y3*y3;
      size_t o = ((size_t)(b0+bb)*COUT + (co0+cg*4+u))*LSEQ + l0 + lt*4;
      st4(out + o, y0, y1, y2, y3);
    }
  }
  const int lane = tid & 63;
  #pragma unroll
  for (int off = 1; off < 16; off <<= 1) {
    #pragma unroll
    for (int u=0; u<4; ++u) {
      p1[u] += __shfl_xor(p1[u], off, 64);
      p2[u] += __shfl_xor(p2[u], off, 64);
    }
  }
  if ((lane & 15) == 0) {
    #pragma unroll
    for (int u=0; u<4; ++u) {
      atomicAdd(&S1[co0+cg*4+u], p1[u]);
      atomicAdd(&S2[co0+cg*4+u], p2[u]);
    }
  }
}

// ---------- batchnorm finalize: scale/shift from sums ----------
__global__ void finalize_stats(const float* __restrict__ S1, const float* __restrict__ S2,
                               const float* __restrict__ g, const float* __restrict__ be,
                               float* __restrict__ scale, float* __restrict__ shift, int C)
{
  int c = threadIdx.x;
  if (c < C) {
    const float invN = 1.f / 65536.f;
    float m = S1[c] * invN;
    float var = fmaxf(S2[c] * invN - m*m, 0.f);
    float sc = g[c] / sqrtf(var + 1e-5f);
    scale[c] = sc;
    shift[c] = be[c] - m * sc;
  }
}

__global__ void zero_stats(float* __restrict__ p, int n){
  int i = blockIdx.x*256 + threadIdx.x;
  if (i < n) p[i] = 0.f;
}

// ---------- feat = mean_L relu(bn(a5)) ----------
template<typename T>
__global__ __launch_bounds__(256)
void feat_kernel(const T* __restrict__ a, const float* __restrict__ scale,
                 const float* __restrict__ shift, float* __restrict__ feat)
{
  int b = blockIdx.y;
  int c = blockIdx.x*32 + (threadIdx.x >> 3);
  int lp = threadIdx.x & 7;
  const T* p = a + ((size_t)b*256 + c)*LSEQ;
  float sc = scale[c], sh = shift[c], sum = 0.f;
  for (int i = 0; i < 64; ++i) {
    int base = (i*8 + lp)*4;
    float v0,v1,v2,v3;
    ld4(p + base, v0,v1,v2,v3);
    sum += fmaxf(fmaf(v0,sc,sh),0.f) + fmaxf(fmaf(v1,sc,sh),0.f)
         + fmaxf(fmaf(v2,sc,sh),0.f) + fmaxf(fmaf(v3,sc,sh),0.f);
  }
  #pragma unroll
  for (int off = 1; off < 8; off <<= 1) sum += __shfl_xor(sum, off, 64);
  if (lp == 0) feat[b*256 + c] = sum * (1.f/(float)LSEQ);
}

// ---------- head: two 32x64x256 GEMVs ----------
__global__ __launch_bounds__(256)
void head_kernel(const float* __restrict__ feat, const float* __restrict__ wm,
                 const float* __restrict__ bm, const float* __restrict__ wv,
                 const float* __restrict__ bv, float* __restrict__ out)
{
  int idx = blockIdx.x*256 + threadIdx.x;   // 4096 outputs
  int sel = idx >> 11, rem = idx & 2047, b = rem >> 6, j = rem & 63;
  const float* W = sel ? wv : wm;
  const float* bias = sel ? bv : bm;
  const float4* f = (const float4*)(feat + b*256);
  const float4* wr = (const float4*)(W + j*256);
  float acc = 0.f;
  #pragma unroll 4
  for (int c = 0; c < 64; ++c) {
    float4 a4 = f[c], w4 = wr[c];
    acc += a4.x*w4.x + a4.y*w4.y + a4.z*w4.z + a4.w*w4.w;
  }
  out[idx] = acc + bias[j];
}

// ---------- host pipeline ----------
template<typename T>
static void run_pipeline(void* const* d_in, void* d_out, void* d_ws, hipStream_t stream)
{
  const float* x = (const float*)d_in[0];
  const float *cw[6], *cbp[6], *bg[6], *bb[6];
  for (int i=0;i<6;i++){
    cw[i]=(const float*)d_in[1+4*i]; cbp[i]=(const float*)d_in[2+4*i];
    bg[i]=(const float*)d_in[3+4*i]; bb[i]=(const float*)d_in[4+4*i];
  }
  const float* wm=(const float*)d_in[25]; const float* bm=(const float*)d_in[26];
  const float* wv=(const float*)d_in[27]; const float* bv=(const float*)d_in[28];

  char* ws = (char*)d_ws;
  size_t off = 0;
  float* h0 = (float*)(ws+off); off += (size_t)NB*LSEQ*4;
  T* bufA = (T*)(ws+off); off += (size_t)NB*256*LSEQ*sizeof(T);
  T* bufB = (T*)(ws+off); off += (size_t)NB*256*LSEQ*sizeof(T);
  float* stats = (float*)(ws+off); off += 3072*4;
  float* scale = (float*)(ws+off); off += 1536*4;
  float* shift = (float*)(ws+off); off += 1536*4;
  float* feat  = (float*)(ws+off); off += (size_t)NB*256*4;
  float* S1 = stats; float* S2 = stats + 1536;

  zero_stats<<<12,256,0,stream>>>(stats, 3072);
  row_prep<<<NB,256,0,stream>>>(x, h0);

  conv_bn<1,64,5,1,false,float,T><<<dim3(32,1,8),256,0,stream>>>(h0, cw[0], cbp[0], nullptr, nullptr, bufA, S1+0, S2+0);
  finalize_stats<<<1,256,0,stream>>>(S1+0,   S2+0,   bg[0], bb[0], scale+0,    shift+0,    64);
  conv_bn<64,64,5,4,true,T,T><<<dim3(32,1,8),256,0,stream>>>(bufA, cw[1], cbp[1], scale+0, shift+0, bufB, S1+256, S2+256);
  finalize_stats<<<1,256,0,stream>>>(S1+256, S2+256, bg[1], bb[1], scale+256,  shift+256,  64);
  conv_bn<64,128,15,4,true,T,T><<<dim3(32,2,8),256,0,stream>>>(bufB, cw[2], cbp[2], scale+256, shift+256, bufA, S1+512, S2+512);
  finalize_stats<<<1,256,0,stream>>>(S1+512, S2+512, bg[2], bb[2], scale+512,  shift+512,  128);
  conv_bn<128,128,15,4,true,T,T><<<dim3(32,2,8),256,0,stream>>>(bufA, cw[3], cbp[3], scale+512, shift+512, bufB, S1+768, S2+768);
  finalize_stats<<<1,256,0,stream>>>(S1+768, S2+768, bg[3], bb[3], scale+768,  shift+768,  128);
  conv_bn<128,256,25,4,true,T,T><<<dim3(32,4,8),256,0,stream>>>(bufB, cw[4], cbp[4], scale+768, shift+768, bufA, S1+1024, S2+1024);
  finalize_stats<<<1,256,0,stream>>>(S1+1024,S2+1024,bg[4], bb[4], scale+1024, shift+1024, 256);
  conv_bn<256,256,25,4,true,T,T><<<dim3(32,4,8),256,0,stream>>>(bufA, cw[5], cbp[5], scale+1024, shift+1024, bufB, S1+1280, S2+1280);
  finalize_stats<<<1,256,0,stream>>>(S1+1280,S2+1280,bg[5], bb[5], scale+1280, shift+1280, 256);

  feat_kernel<T><<<dim3(8,NB),256,0,stream>>>(bufB, scale+1280, shift+1280, feat);
  head_kernel<<<16,256,0,stream>>>(feat, wm, bm, wv, bv, (float*)d_out);
}

extern "C" void kernel_launch(void* const* d_in, const int* in_sizes, int n_in,
                              void* d_out, int out_size, void* d_ws, size_t ws_size,
                              hipStream_t stream)
{
  (void)in_sizes; (void)n_in; (void)out_size;
  size_t need_f32 = (size_t)NB*LSEQ*4 + 2*(size_t)NB*256*LSEQ*4 + 3072*4 + 2*1536*4 + (size_t)NB*256*4;
  if (ws_size >= need_f32) run_pipeline<float>(d_in, d_out, d_ws, stream);
  else                     run_pipeline<__hip_bfloat16>(d_in, d_out, d_ws, stream);
}

// Round 2
// 1005.151 us; speedup vs baseline: 5.2548x; 5.2548x over previous
//
#include <hip/hip_runtime.h>
#include <hip/hip_bf16.h>

#define LSEQ 2048
#define NB 32

typedef __attribute__((ext_vector_type(8))) short short8v;
typedef __attribute__((ext_vector_type(4))) float float4v;

// ---------- dtype helpers ----------
__device__ __forceinline__ unsigned short f2b(float f){
  __hip_bfloat16 h = __float2bfloat16(f);
  return *reinterpret_cast<unsigned short*>(&h);
}
__device__ __forceinline__ float b2f_bits(unsigned short u){
  unsigned int x = ((unsigned int)u) << 16; return __uint_as_float(x);
}

__device__ __forceinline__ float wave_min(float v){
  #pragma unroll
  for (int off = 32; off; off >>= 1) v = fminf(v, __shfl_xor(v, off, 64));
  return v;
}

// apply BN(scale,shift)+relu to 8 bf16 packed in uint4, repack to bf16
__device__ __forceinline__ uint4 bn_pack(uint4 g, const float* sc, const float* sh, int cbase){
  union { uint4 u; unsigned short us[8]; } in_, out_;
  in_.u = g;
  #pragma unroll
  for (int j = 0; j < 8; ++j){
    float v = b2f_bits(in_.us[j]);
    v = fmaxf(fmaf(v, sc[cbase+j], sh[cbase+j]), 0.f);
    out_.us[j] = f2b(v);
  }
  return out_.u;
}

// ---------- row preprocessing: stats + find_peaks + normalize ----------
__global__ __launch_bounds__(256)
void row_prep(const float* __restrict__ x, float* __restrict__ h0)
{
  const int b = blockIdx.x, tid = threadIdx.x;
  const int lane = tid & 63, wid = tid >> 6;
  __shared__ float xs[LSEQ];
  __shared__ unsigned char cand[LSEQ], kA[LSEQ], kB[LSEQ], peaks[LSEQ];
  __shared__ int s_list[256];
  __shared__ int s_changed, s_cnt;
  __shared__ float s_redA[4], s_redB[4];
  __shared__ float s_mx, s_mean, s_std;

  const float* xr = x + (size_t)b * LSEQ;
  for (int i = tid; i < LSEQ/4; i += 256) ((float4*)xs)[i] = ((const float4*)xr)[i];
  __syncthreads();

  float vmax = -__builtin_inff(), vsum = 0.f;
  for (int i = tid; i < LSEQ; i += 256) { float v = xs[i]; vmax = fmaxf(vmax, v); vsum += v; }
  #pragma unroll
  for (int off = 32; off; off >>= 1){
    vmax = fmaxf(vmax, __shfl_xor(vmax, off, 64));
    vsum += __shfl_xor(vsum, off, 64);
  }
  if (lane == 0){ s_redA[wid] = vmax; s_redB[wid] = vsum; }
  __syncthreads();
  if (tid == 0){
    s_mx   = fmaxf(fmaxf(s_redA[0], s_redA[1]), fmaxf(s_redA[2], s_redA[3]));
    s_mean = (s_redB[0]+s_redB[1]+s_redB[2]+s_redB[3]) * (1.f/(float)LSEQ);
  }
  __syncthreads();
  const float m = s_mean, mx = s_mx;

  float vss = 0.f;
  for (int i = tid; i < LSEQ; i += 256){ float d = xs[i]-m; vss += d*d; }
  #pragma unroll
  for (int off = 32; off; off >>= 1) vss += __shfl_xor(vss, off, 64);
  if (lane == 0) s_redA[wid] = vss;
  __syncthreads();
  if (tid == 0) s_std = sqrtf((s_redA[0]+s_redA[1]+s_redA[2]+s_redA[3]) / (float)(LSEQ-1));
  __syncthreads();
  const float sd = s_std;

  const float hthr = 0.1f * mx;
  for (int i = tid; i < LSEQ; i += 256) {
    unsigned char c = 0;
    if (i >= 1 && i <= LSEQ-2) {
      float v = xs[i];
      c = (v > xs[i-1]) && (v > xs[i+1]) && (v >= hthr);
    }
    cand[i] = c; kA[i] = c; peaks[i] = 0;
  }
  if (tid == 0) s_changed = 0;
  __syncthreads();

  unsigned char* cur = kA; unsigned char* nxt = kB;
  for (int it = 0; it < LSEQ; ++it) {
    int ch = 0;
    for (int i = tid; i < LSEQ; i += 256) {
      unsigned char nk = cand[i];
      if (nk) {
        float xi = xs[i];
        int j0 = (i-9 < 0) ? 0 : i-9;
        int j1 = (i+9 > LSEQ-1) ? LSEQ-1 : i+9;
        for (int j = j0; j <= j1; ++j) {
          if (j == i) continue;
          if (cur[j] && (xs[j] > xi || (xs[j] == xi && j < i))) { nk = 0; break; }
        }
      }
      nxt[i] = nk;
      ch |= (nk != cur[i]);
    }
    if (ch) s_changed = 1;
    __syncthreads();
    int chg = s_changed;
    __syncthreads();
    if (tid == 0) s_changed = 0;
    unsigned char* t_ = cur; cur = nxt; nxt = t_;
    __syncthreads();
    if (!chg) break;
  }

  if (tid == 0) s_cnt = 0;
  __syncthreads();
  for (int i = tid; i < LSEQ; i += 256)
    if (cur[i]) { int s = atomicAdd(&s_cnt, 1); if (s < 256) s_list[s] = i; }
  __syncthreads();
  int M = s_cnt; if (M > 256) M = 256;
  const float pthr = 0.05f * mx;

  for (int c = wid; c < M; c += 4) {
    int p = s_list[c]; float xp = xs[p];
    float lmin = xp;
    for (int s = 0;; ++s) {
      int idx = p - 64*(s+1) + lane;
      bool valid = idx >= 0;
      float v = valid ? xs[idx] : 0.f;
      unsigned long long mk = __ballot(valid && (v > xp));
      if (mk) {
        int hb = 63 - __builtin_clzll(mk);
        float v2 = (lane > hb) ? v : __builtin_inff();
        lmin = fminf(lmin, wave_min(v2));
        break;
      }
      float v2 = valid ? v : __builtin_inff();
      lmin = fminf(lmin, wave_min(v2));
      if (p - 64*(s+1) <= 0) break;
    }
    float rmin = xp;
    for (int s = 0;; ++s) {
      int idx = p + 1 + 64*s + lane;
      bool valid = idx < LSEQ;
      float v = valid ? xs[idx] : 0.f;
      unsigned long long mk = __ballot(valid && (v > xp));
      if (mk) {
        int lb_ = __builtin_ctzll(mk);
        float v2 = (lane < lb_) ? v : __builtin_inff();
        rmin = fminf(rmin, wave_min(v2));
        break;
      }
      float v2 = valid ? v : __builtin_inff();
      rmin = fminf(rmin, wave_min(v2));
      if (p + 64 + 64*s >= LSEQ-1) break;
    }
    if (lane == 0 && (xp - fmaxf(lmin, rmin)) >= pthr) peaks[p] = 1;
  }
  __syncthreads();

  const float inv = 1.f / (sd + 1e-5f);
  for (int i = tid; i < LSEQ; i += 256) {
    float w_ = 1.f + 0.1f * (float)peaks[i];
    h0[(size_t)b*LSEQ + i] = (w_ * (xs[i] - m)) * inv;
  }
}

// ---------- weight convert fp32 [co][ci][k] -> bf16 [t][co][ci] ----------
__global__ void wconv(const float* __restrict__ w, __hip_bfloat16* __restrict__ o,
                      int COUT, int CIN, int K)
{
  int i = blockIdx.x*256 + threadIdx.x;
  int tot = COUT*CIN*K;
  if (i < tot){
    int t = i / (COUT*CIN); int r = i - t*COUT*CIN; int co = r / CIN; int ci = r - co*CIN;
    o[i] = __float2bfloat16(w[(co*CIN + ci)*K + t]);
  }
}

// ---------- conv0: 1->64, K=5, scalar ----------
__global__ __launch_bounds__(256)
void conv0_kernel(const float* __restrict__ h0, const float* __restrict__ w,
                  const float* __restrict__ cb, __hip_bfloat16* __restrict__ out,
                  float* __restrict__ S1, float* __restrict__ S2)
{
  __shared__ float sw[320], sb[64];
  __shared__ float red[2][4][64];
  const int tid = threadIdx.x, lane = tid & 63, wv = tid >> 6;
  for (int i = tid; i < 320; i += 256) sw[i] = w[i];
  if (tid < 64) sb[tid] = cb[tid];
  __syncthreads();
  const int b = blockIdx.y;
  const float* xr = h0 + (size_t)b * LSEQ;
  float s1 = 0.f, s2 = 0.f;
  #pragma unroll
  for (int q = 0; q < 4; ++q) {
    int pos = blockIdx.x*16 + q*4 + wv;
    float xv[5];
    #pragma unroll
    for (int k = 0; k < 5; ++k) {
      int gp = pos - 2 + k;
      xv[k] = (gp >= 0 && gp < LSEQ) ? xr[gp] : 0.f;
    }
    float y = sb[lane];
    #pragma unroll
    for (int k = 0; k < 5; ++k) y = fmaf(sw[lane*5+k], xv[k], y);
    out[((size_t)b*LSEQ + pos)*64 + lane] = __float2bfloat16(y);
    s1 += y; s2 += y*y;
  }
  red[0][wv][lane] = s1; red[1][wv][lane] = s2;
  __syncthreads();
  if (wv == 0) {
    s1 = red[0][0][lane]+red[0][1][lane]+red[0][2][lane]+red[0][3][lane];
    s2 = red[1][0][lane]+red[1][1][lane]+red[1][2][lane]+red[1][3][lane];
    atomicAdd(&S1[lane], s1);
    atomicAdd(&S2[lane], s2);
  }
}

// ---------- MFMA implicit-GEMM conv ----------
// in:  [NB][LSEQ][CIN] bf16 (pre-BN activations of previous layer)
// wb:  [K][COUT][CIN] bf16
// out: [NB][LSEQ][COUT] bf16 (pre-BN), stats S1/S2 accumulated in fp32
template<int CIN, int COUT, int K, int BM>
__global__ __launch_bounds__(256, 2)
void conv_mfma(const __hip_bfloat16* __restrict__ in,
               const __hip_bfloat16* __restrict__ wb,
               const float* __restrict__ cb,
               const float* __restrict__ scale,
               const float* __restrict__ shift,
               __hip_bfloat16* __restrict__ out,
               float* __restrict__ S1, float* __restrict__ S2)
{
  constexpr int PAD = K/2, XR = 256 + K - 1;
  constexpr int WM_T = BM/2, MF = WM_T/16, NF = 8;
  constexpr int WCH = BM/32;           // 16B weight chunks per thread per tap

  __shared__ float s_sc[CIN], s_sh[CIN];
  __shared__ alignas(16) char XsB[XR*128];       // [row=pos][64 ci] bf16, XOR-swizzled
  __shared__ alignas(16) char WsB[2][BM*128];    // [row=co][64 ci] bf16, XOR-swizzled

  const int tid = threadIdx.x;
  const int lane = tid & 63;
  const int wid = tid >> 6;
  const int wm = wid >> 1, wn = wid & 1;
  const int b = blockIdx.z;
  const int p0 = blockIdx.x * 256;
  const int co0 = blockIdx.y * BM;
  const int colp = lane & 15, rgrp = lane >> 4;

  for (int i = tid; i < CIN; i += 256) { s_sc[i] = scale[i]; s_sh[i] = shift[i]; }

  float4v acc[MF][NF];
  #pragma unroll
  for (int mf = 0; mf < MF; ++mf)
    #pragma unroll
    for (int nf = 0; nf < NF; ++nf) acc[mf][nf] = (float4v){0.f,0.f,0.f,0.f};

  const size_t brow = (size_t)b * LSEQ;

  for (int cic = 0; cic < CIN; cic += 64) {
    __syncthreads();
    // stage X tile (BN+relu folded), 16B chunks, swizzled
    for (int c = tid; c < XR*8; c += 256) {
      int r = c >> 3, ch = c & 7;
      int gp = p0 - PAD + r;
      uint4 v = make_uint4(0u,0u,0u,0u);
      if (gp >= 0 && gp < LSEQ) {
        v = *(const uint4*)(in + (brow + gp)*CIN + cic + ch*8);
        v = bn_pack(v, s_sc, s_sh, cic + ch*8);
      }
      *(uint4*)(XsB + r*128 + ((ch*16) ^ ((r&7)<<4))) = v;
    }
    // stage weights tap 0 into buf 0
    #pragma unroll
    for (int c0 = 0; c0 < WCH; ++c0) {
      int cc = tid + c0*256;
      int r = cc >> 3, ch = cc & 7;
      uint4 v = *(const uint4*)(wb + ((size_t)co0 + r)*CIN + cic + ch*8);
      *(uint4*)(WsB[0] + r*128 + ((ch*16) ^ ((r&7)<<4))) = v;
    }
    __syncthreads();
    int cur = 0;
    for (int t = 0; t < K; ++t) {
      uint4 wreg[WCH];
      if (t+1 < K) {       // issue next-tap weight loads early (hide under MFMA)
        #pragma unroll
        for (int c0 = 0; c0 < WCH; ++c0) {
          int cc = tid + c0*256;
          int r = cc >> 3, ch = cc & 7;
          wreg[c0] = *(const uint4*)(wb + (((size_t)(t+1)*COUT) + co0 + r)*CIN + cic + ch*8);
        }
      }
      #pragma unroll
      for (int kk = 0; kk < 2; ++kk) {
        short8v af[MF], bfr[NF];
        #pragma unroll
        for (int mf = 0; mf < MF; ++mf) {
          int row = wm*WM_T + mf*16 + colp;
          af[mf] = *(const short8v*)(WsB[cur] + row*128 + ((kk*64 + rgrp*16) ^ ((row&7)<<4)));
        }
        #pragma unroll
        for (int nf = 0; nf < NF; ++nf) {
          int rr = wn*128 + nf*16 + colp + t;
          bfr[nf] = *(const short8v*)(XsB + rr*128 + ((kk*64 + rgrp*16) ^ ((rr&7)<<4)));
        }
        #pragma unroll
        for (int mf = 0; mf < MF; ++mf)
          #pragma unroll
          for (int nf = 0; nf < NF; ++nf)
            acc[mf][nf] = __builtin_amdgcn_mfma_f32_16x16x32_bf16(af[mf], bfr[nf], acc[mf][nf], 0, 0, 0);
      }
      if (t+1 < K) {
        #pragma unroll
        for (int c0 = 0; c0 < WCH; ++c0) {
          int cc = tid + c0*256;
          int r = cc >> 3, ch = cc & 7;
          *(uint4*)(WsB[cur^1] + r*128 + ((ch*16) ^ ((r&7)<<4))) = wreg[c0];
        }
      }
      __syncthreads();
      cur ^= 1;
    }
  }

  // epilogue: bias, bf16 store [b][pos][co], fp32 stats
  #pragma unroll
  for (int mf = 0; mf < MF; ++mf) {
    int co_b = co0 + wm*WM_T + mf*16 + rgrp*4;
    float b0 = cb[co_b+0], b1 = cb[co_b+1], b2 = cb[co_b+2], b3 = cb[co_b+3];
    float s1v[4] = {0,0,0,0}, s2v[4] = {0,0,0,0};
    #pragma unroll
    for (int nf = 0; nf < NF; ++nf) {
      int pos = p0 + wn*128 + nf*16 + colp;
      float y0 = acc[mf][nf][0] + b0;
      float y1 = acc[mf][nf][1] + b1;
      float y2 = acc[mf][nf][2] + b2;
      float y3 = acc[mf][nf][3] + b3;
      ushort4 pk = make_ushort4(f2b(y0), f2b(y1), f2b(y2), f2b(y3));
      *(ushort4*)(out + (brow + pos)*COUT + co_b) = pk;
      s1v[0]+=y0; s1v[1]+=y1; s1v[2]+=y2; s1v[3]+=y3;
      s2v[0]+=y0*y0; s2v[1]+=y1*y1; s2v[2]+=y2*y2; s2v[3]+=y3*y3;
    }
    #pragma unroll
    for (int off = 1; off < 16; off <<= 1) {
      #pragma unroll
      for (int r = 0; r < 4; ++r) {
        s1v[r] += __shfl_xor(s1v[r], off, 64);
        s2v[r] += __shfl_xor(s2v[r], off, 64);
      }
    }
    if (colp == 0) {
      #pragma unroll
      for (int r = 0; r < 4; ++r) {
        atomicAdd(&S1[co_b+r], s1v[r]);
        atomicAdd(&S2[co_b+r], s2v[r]);
      }
    }
  }
}

// ---------- batchnorm finalize ----------
__global__ void finalize_stats(const float* __restrict__ S1, const float* __restrict__ S2,
                               const float* __restrict__ g, const float* __restrict__ be,
                               float* __restrict__ scale, float* __restrict__ shift, int C)
{
  int c = threadIdx.x;
  if (c < C) {
    const float invN = 1.f / 65536.f;
    float m = S1[c] * invN;
    float var = fmaxf(S2[c] * invN - m*m, 0.f);
    float sc = g[c] / sqrtf(var + 1e-5f);
    scale[c] = sc;
    shift[c] = be[c] - m * sc;
  }
}

__global__ void zero_ws(float* __restrict__ p, int n){
  int i = blockIdx.x*256 + threadIdx.x;
  if (i < n) p[i] = 0.f;
}

// ---------- feat: accumulate sum over L of relu(bn(a5)) ----------
__global__ __launch_bounds__(256)
void feat_accum(const __hip_bfloat16* __restrict__ a,
                const float* __restrict__ scale, const float* __restrict__ shift,
                float* __restrict__ feat)
{
  const int b = blockIdx.y, chunk = blockIdx.x, c = threadIdx.x;
  float sc = scale[c], sh = shift[c], s = 0.f;
  const __hip_bfloat16* p = a + ((size_t)b*LSEQ + chunk*256)*256 + c;
  #pragma unroll 4
  for (int i = 0; i < 256; ++i)
    s += fmaxf(fmaf(__bfloat162float(p[(size_t)i*256]), sc, sh), 0.f);
  atomicAdd(&feat[b*256 + c], s);
}

// ---------- head: two 32x64x256 GEMVs (feat holds sums, scale by 1/L) ----------
__global__ __launch_bounds__(256)
void head_kernel(const float* __restrict__ feat, const float* __restrict__ wm,
                 const float* __restrict__ bm, const float* __restrict__ wv,
                 const float* __restrict__ bv, float* __restrict__ out)
{
  int idx = blockIdx.x*256 + threadIdx.x;
  int sel = idx >> 11, rem = idx & 2047, b = rem >> 6, j = rem & 63;
  const float* W = sel ? wv : wm;
  const float* bias = sel ? bv : bm;
  const float4* f = (const float4*)(feat + b*256);
  const float4* wr = (const float4*)(W + j*256);
  float acc = 0.f;
  #pragma unroll 4
  for (int c = 0; c < 64; ++c) {
    float4 a4 = f[c], w4 = wr[c];
    acc += a4.x*w4.x + a4.y*w4.y + a4.z*w4.z + a4.w*w4.w;
  }
  out[idx] = acc * (1.f/(float)LSEQ) + bias[j];
}

extern "C" void kernel_launch(void* const* d_in, const int* in_sizes, int n_in,
                              void* d_out, int out_size, void* d_ws, size_t ws_size,
                              hipStream_t stream)
{
  (void)in_sizes; (void)n_in; (void)out_size; (void)ws_size;
  const float* x = (const float*)d_in[0];
  const float *cw[6], *cbp[6], *bg[6], *bb[6];
  for (int i = 0; i < 6; i++){
    cw[i]=(const float*)d_in[1+4*i]; cbp[i]=(const float*)d_in[2+4*i];
    bg[i]=(const float*)d_in[3+4*i]; bb[i]=(const float*)d_in[4+4*i];
  }
  const float* wmh=(const float*)d_in[25]; const float* bmh=(const float*)d_in[26];
  const float* wvh=(const float*)d_in[27]; const float* bvh=(const float*)d_in[28];

  char* ws = (char*)d_ws;
  size_t off = 0;
  float* h0 = (float*)(ws+off);            off += (size_t)NB*LSEQ*4;
  __hip_bfloat16* bufA = (__hip_bfloat16*)(ws+off); off += (size_t)NB*LSEQ*256*2;
  __hip_bfloat16* bufB = (__hip_bfloat16*)(ws+off); off += (size_t)NB*LSEQ*256*2;
  __hip_bfloat16* wb1 = (__hip_bfloat16*)(ws+off); off += (size_t)5*64*64*2;
  __hip_bfloat16* wb2 = (__hip_bfloat16*)(ws+off); off += (size_t)15*128*64*2;
  __hip_bfloat16* wb3 = (__hip_bfloat16*)(ws+off); off += (size_t)15*128*128*2;
  __hip_bfloat16* wb4 = (__hip_bfloat16*)(ws+off); off += (size_t)25*256*128*2;
  __hip_bfloat16* wb5 = (__hip_bfloat16*)(ws+off); off += (size_t)25*256*256*2;
  float* stats = (float*)(ws+off);         off += 3072*4;
  float* feat  = (float*)(ws+off);         off += (size_t)NB*256*4;   // contiguous with stats
  float* scale = (float*)(ws+off);         off += 1536*4;
  float* shift = (float*)(ws+off);         off += 1536*4;
  float* S1 = stats; float* S2 = stats + 1536;

  // zero stats + feat (contiguous 3072 + 8192 floats)
  zero_ws<<<44, 256, 0, stream>>>(stats, 11264);

  // weight conversions
  wconv<<<(5*64*64+255)/256,   256, 0, stream>>>(cw[1], wb1, 64, 64, 5);
  wconv<<<(15*128*64+255)/256, 256, 0, stream>>>(cw[2], wb2, 128, 64, 15);
  wconv<<<(15*128*128+255)/256,256, 0, stream>>>(cw[3], wb3, 128, 128, 15);
  wconv<<<(25*256*128+255)/256,256, 0, stream>>>(cw[4], wb4, 256, 128, 25);
  wconv<<<(25*256*256+255)/256,256, 0, stream>>>(cw[5], wb5, 256, 256, 25);

  row_prep<<<NB, 256, 0, stream>>>(x, h0);

  conv0_kernel<<<dim3(128, NB), 256, 0, stream>>>(h0, cw[0], cbp[0], bufA, S1+0, S2+0);
  finalize_stats<<<1,256,0,stream>>>(S1+0,    S2+0,    bg[0], bb[0], scale+0,    shift+0,    64);

  conv_mfma<64,64,5,64><<<dim3(8,1,NB),256,0,stream>>>(bufA, wb1, cbp[1], scale+0, shift+0, bufB, S1+256, S2+256);
  finalize_stats<<<1,256,0,stream>>>(S1+256,  S2+256,  bg[1], bb[1], scale+256,  shift+256,  64);

  conv_mfma<64,128,15,128><<<dim3(8,1,NB),256,0,stream>>>(bufB, wb2, cbp[2], scale+256, shift+256, bufA, S1+512, S2+512);
  finalize_stats<<<1,256,0,stream>>>(S1+512,  S2+512,  bg[2], bb[2], scale+512,  shift+512,  128);

  conv_mfma<128,128,15,128><<<dim3(8,1,NB),256,0,stream>>>(bufA, wb3, cbp[3], scale+512, shift+512, bufB, S1+768, S2+768);
  finalize_stats<<<1,256,0,stream>>>(S1+768,  S2+768,  bg[3], bb[3], scale+768,  shift+768,  128);

  conv_mfma<128,256,25,128><<<dim3(8,2,NB),256,0,stream>>>(bufB, wb4, cbp[4], scale+768, shift+768, bufA, S1+1024, S2+1024);
  finalize_stats<<<1,256,0,stream>>>(S1+1024, S2+1024, bg[4], bb[4], scale+1024, shift+1024, 256);

  conv_mfma<256,256,25,128><<<dim3(8,2,NB),256,0,stream>>>(bufA, wb5, cbp[5], scale+1024, shift+1024, bufB, S1+1280, S2+1280);
  finalize_stats<<<1,256,0,stream>>>(S1+1280, S2+1280, bg[5], bb[5], scale+1280, shift+1280, 256);

  feat_accum<<<dim3(8, NB), 256, 0, stream>>>(bufB, scale+1280, shift+1280, feat);
  head_kernel<<<16, 256, 0, stream>>>(feat, wmh, bmh, wvh, bvh, (float*)d_out);
}